// Round 7
// baseline (137.672 us; speedup 1.0000x reference)
//
#include <hip/hip_runtime.h>
#include <math.h>

#define B_   4
#define L_   1024
#define HID_ 768
#define NH_  12
#define D_   64
#define SCALE_ 0.125f
#define NEGV (-1e15f)

typedef __attribute__((ext_vector_type(4))) float  f32x4;
typedef __attribute__((ext_vector_type(8))) __bf16 bf16x8;
typedef __attribute__((ext_vector_type(8))) unsigned short ushort8v;
typedef __attribute__((ext_vector_type(4))) unsigned short ushort4v;

typedef const __attribute__((address_space(1))) unsigned int* gas1_t;
typedef __attribute__((address_space(3))) unsigned int*       las3_t;
#define GLDS16(g, l) __builtin_amdgcn_global_load_lds((gas1_t)(g), (las3_t)(l), 16, 0, 0)

static __device__ __forceinline__ unsigned short f2bf(float f) {
    unsigned int u = __builtin_bit_cast(unsigned int, f);
    u += 0x7fffu + ((u >> 16) & 1u);           // RNE
    return (unsigned short)(u >> 16);
}

// ---------------------------------------------------------------------------
// inp f32 -> bf16
// ---------------------------------------------------------------------------
__global__ __launch_bounds__(256) void convert_x_kernel(
    const float* __restrict__ in, unsigned short* __restrict__ out, int n4)
{
    int i = blockIdx.x * 256 + threadIdx.x;
    if (i < n4) {
        float4 v = reinterpret_cast<const float4*>(in)[i];
        ushort4v o;
        o.x = f2bf(v.x); o.y = f2bf(v.y); o.z = f2bf(v.z); o.w = f2bf(v.w);
        reinterpret_cast<ushort4v*>(out)[i] = o;
    }
}

// ---------------------------------------------------------------------------
// W f32 [768 in][768 out] -> Wt bf16 [768 out][768 in]. grid (12,12,6).
// ---------------------------------------------------------------------------
struct WArgs { const float* w[6]; unsigned short* wt[6]; };

__global__ __launch_bounds__(256) void transpose_w_kernel(WArgs a)
{
    const float* W = a.w[blockIdx.z];
    unsigned short* Wt = a.wt[blockIdx.z];
    __shared__ float t[64][65];
    const int tid = threadIdx.x;
    const int lr = tid >> 2, lc4 = (tid & 3) * 16;
    const int r0 = blockIdx.y * 64, c0 = blockIdx.x * 64;
#pragma unroll
    for (int j = 0; j < 4; ++j) {
        float4 v = *reinterpret_cast<const float4*>(&W[(size_t)(r0 + lr) * HID_ + c0 + lc4 + j * 4]);
        t[lr][lc4 + j * 4 + 0] = v.x;
        t[lr][lc4 + j * 4 + 1] = v.y;
        t[lr][lc4 + j * 4 + 2] = v.z;
        t[lr][lc4 + j * 4 + 3] = v.w;
    }
    __syncthreads();
    unsigned short tmp[16];
#pragma unroll
    for (int j = 0; j < 16; ++j) tmp[j] = f2bf(t[lc4 + j][lr]);
    unsigned short* dst = &Wt[(size_t)(c0 + lr) * HID_ + r0 + lc4];
    *reinterpret_cast<ushort8v*>(dst)     = *reinterpret_cast<ushort8v*>(&tmp[0]);
    *reinterpret_cast<ushort8v*>(dst + 8) = *reinterpret_cast<ushort8v*>(&tmp[8]);
}

// ---------------------------------------------------------------------------
// bf16 GEMM (unchanged from round 6): 64x128 tile, BK=64, grid (64,6,z).
// ---------------------------------------------------------------------------
struct GemmJob {
    const unsigned short* A;
    const unsigned short* Wt;
    const float* bias;
    void* C;
    int mode;
    int relu;
    float scale;
};
struct GemmArgs { GemmJob j[3]; };

__global__ __launch_bounds__(256, 4) void gemm_bf16_kernel(GemmArgs args)
{
    const GemmJob jb = args.j[blockIdx.z];
    __shared__ unsigned short As[64 * 64];
    __shared__ unsigned short Bs[128 * 64];

    const int tid = threadIdx.x;
    const int w = tid >> 6, lane = tid & 63, g = lane >> 4, lq = lane & 15;
    const int m0 = blockIdx.x * 64, n0 = blockIdx.y * 128;

    f32x4 acc[4][2];
#pragma unroll
    for (int i = 0; i < 4; ++i)
#pragma unroll
        for (int j = 0; j < 2; ++j) acc[i][j] = (f32x4){0.f, 0.f, 0.f, 0.f};

    const int sr = tid >> 3;
    const int kq = ((tid & 7) ^ (sr & 7)) * 8;
    const unsigned short* Ap0 = jb.A  + (size_t)(m0 + sr) * HID_ + kq;
    const unsigned short* Ap1 = jb.A  + (size_t)(m0 + 32 + sr) * HID_ + kq;
    const unsigned short* Bp0 = jb.Wt + (size_t)(n0 + sr) * HID_ + kq;
    const unsigned short* Bp1 = jb.Wt + (size_t)(n0 + 32 + sr) * HID_ + kq;
    const unsigned short* Bp2 = jb.Wt + (size_t)(n0 + 64 + sr) * HID_ + kq;
    const unsigned short* Bp3 = jb.Wt + (size_t)(n0 + 96 + sr) * HID_ + kq;
    char* AsB = (char*)As;
    char* BsB = (char*)Bs;
    const int wb = w * 1024;

    for (int k0 = 0; k0 < HID_; k0 += 64) {
        __syncthreads();
        GLDS16(Ap0 + k0, AsB + wb);
        GLDS16(Ap1 + k0, AsB + 4096 + wb);
        GLDS16(Bp0 + k0, BsB + wb);
        GLDS16(Bp1 + k0, BsB + 4096 + wb);
        GLDS16(Bp2 + k0, BsB + 8192 + wb);
        GLDS16(Bp3 + k0, BsB + 12288 + wb);
        __syncthreads();

#pragma unroll
        for (int ks = 0; ks < 2; ++ks) {
            bf16x8 af[4], bf[2];
#pragma unroll
            for (int mi = 0; mi < 4; ++mi) {
                int row = mi * 16 + lq;
                int c = (ks * 4 + g) ^ (row & 7);
                af[mi] = *reinterpret_cast<const bf16x8*>(&As[row * 64 + c * 8]);
            }
#pragma unroll
            for (int ni = 0; ni < 2; ++ni) {
                int row = w * 32 + ni * 16 + lq;
                int c = (ks * 4 + g) ^ (row & 7);
                bf[ni] = *reinterpret_cast<const bf16x8*>(&Bs[row * 64 + c * 8]);
            }
            __builtin_amdgcn_s_setprio(1);
#pragma unroll
            for (int mi = 0; mi < 4; ++mi)
#pragma unroll
                for (int ni = 0; ni < 2; ++ni)
                    acc[mi][ni] = __builtin_amdgcn_mfma_f32_16x16x32_bf16(
                        af[mi], bf[ni], acc[mi][ni], 0, 0, 0);
            __builtin_amdgcn_s_setprio(0);
        }
    }

    float bcol[2];
#pragma unroll
    for (int ni = 0; ni < 2; ++ni) bcol[ni] = jb.bias[n0 + w * 32 + ni * 16 + lq];

#pragma unroll
    for (int mi = 0; mi < 4; ++mi) {
#pragma unroll
        for (int ni = 0; ni < 2; ++ni) {
            const int n = n0 + w * 32 + ni * 16 + lq;
            float v[4];
#pragma unroll
            for (int r = 0; r < 4; ++r) {
                float x = (acc[mi][ni][r] + bcol[ni]) * jb.scale;
                if (jb.relu) x = fmaxf(x, 0.f);
                v[r] = x;
            }
            const int mbase = m0 + mi * 16 + 4 * g;
            if (jb.mode == 0) {
                float* C = (float*)jb.C;
#pragma unroll
                for (int r = 0; r < 4; ++r)
                    C[(size_t)(mbase + r) * HID_ + n] = v[r];
            } else if (jb.mode == 1) {
                unsigned short* C = (unsigned short*)jb.C;
#pragma unroll
                for (int r = 0; r < 4; ++r)
                    C[(size_t)(mbase + r) * HID_ + n] = f2bf(v[r]);
            } else {
                unsigned short* C = (unsigned short*)jb.C;
                const int bb = mbase >> 10, ltok = mbase & 1023;
                ushort4v o;
                o.x = f2bf(v[0]); o.y = f2bf(v[1]); o.z = f2bf(v[2]); o.w = f2bf(v[3]);
                *reinterpret_cast<ushort4v*>(&C[(size_t)(bb * HID_ + n) * L_ + ltok]) = o;
            }
        }
    }
}

// ---------------------------------------------------------------------------
// Flash attention, bf16 MFMA, async-pipelined staging:
//  - K/V staged by global_load_lds (cannot be sunk; no VGPR round trip) into
//    double-buffered XOR-swizzled LDS [64 rows][8 chunks of 16B]
//  - rel prefetched 1 tile ahead into regs, pinned by sched_barrier(0)
//  - RAW s_barrier (no vmcnt drain) + one counted s_waitcnt vmcnt(36)/tile:
//    next tile's 20 loads stay in flight across the barrier
// Phase: [barX: prev reads done][issue t+1][vmcnt(36): own t landed]
//        [barY: all t landed][compute t]
// Q pre-scaled, in registers. Vt layout [b][h][d][l]. Grid (16, 48).
// ---------------------------------------------------------------------------
__global__ __launch_bounds__(256, 3) void attn_mfma_kernel(
    const unsigned short* __restrict__ Qb, const unsigned short* __restrict__ Kb,
    const unsigned short* __restrict__ Vtb, const float* __restrict__ rel,
    const int* __restrict__ seq_len, const int* __restrict__ lex_num,
    unsigned short* __restrict__ ctx)
{
    const int qt = blockIdx.x, bh = blockIdx.y;
    const int b = bh / NH_, h = bh % NH_;
    const int q0 = qt * 64;
    const int sl = seq_len[b] + lex_num[0];
    const int nkt = (sl + 63) >> 6;
    const int ktmax = nkt - 1;

    __shared__ unsigned short Ks[2][64 * 64];   // [row k][chunk-swizzled d]
    __shared__ unsigned short Vs[2][64 * 64];   // [row d][chunk-swizzled kv]
    __shared__ unsigned short Ps[64 * 72];

    const int tid = threadIdx.x;
    const int w = tid >> 6, lane = tid & 63, g = lane >> 4, lq = lane & 15;
    const int wb = w * 1024;

    // staging maps: chunk c (call0: c=tid, call1: c=256+tid), r=c>>3, cc=c&7,
    // source col-chunk = cc ^ (r&7)  (inverse swizzle at the source, rule #21)
    const int rS0 = tid >> 3,      sw0 = ((tid & 7) ^ (rS0 & 7)) * 8;
    const int rS1 = 32 + (tid >> 3), sw1 = ((tid & 7) ^ (rS1 & 7)) * 8;
    const unsigned short* Kbase = Kb  + (size_t)(b * L_) * HID_ + h * D_;
    const unsigned short* Vbase = Vtb + (size_t)(b * HID_ + h * D_) * L_;
    const unsigned short* Kc0 = Kbase + (size_t)rS0 * HID_ + sw0;
    const unsigned short* Kc1 = Kbase + (size_t)rS1 * HID_ + sw1;
    const unsigned short* Vc0 = Vbase + (size_t)rS0 * L_ + sw0;
    const unsigned short* Vc1 = Vbase + (size_t)rS1 * L_ + sw1;

    const float* relbase = rel + (size_t)bh * (L_ * L_) + (size_t)(q0 + w * 16 + 4 * g) * L_ + lq;

    // Q A-fragments in registers
    bf16x8 aq[2];
#pragma unroll
    for (int ks = 0; ks < 2; ++ks)
        aq[ks] = *reinterpret_cast<const bf16x8*>(
            &Qb[(size_t)(b * L_ + q0 + w * 16 + lq) * HID_ + h * D_ + ks * 32 + g * 8]);

    f32x4 acc[4];
    float m_r[4], l_r[4];
#pragma unroll
    for (int i = 0; i < 4; ++i) {
        acc[i] = (f32x4){0.f, 0.f, 0.f, 0.f};
        m_r[i] = -3e38f; l_r[i] = 0.f;
    }

    float relA[16], relB[16];

    auto stage = [&](int kt_, int p) {
        const size_t k0 = (size_t)kt_ * 64;
        char* KsB = (char*)Ks[p];
        char* VsB = (char*)Vs[p];
        GLDS16(Kc0 + k0 * HID_, KsB + wb);
        GLDS16(Kc1 + k0 * HID_, KsB + 4096 + wb);
        GLDS16(Vc0 + k0,        VsB + wb);
        GLDS16(Vc1 + k0,        VsB + 4096 + wb);
    };
    auto loadrel = [&](int kt_, float (&R)[16]) {
        const size_t k0 = (size_t)kt_ * 64;
#pragma unroll
        for (int ni = 0; ni < 4; ++ni)
#pragma unroll
            for (int r = 0; r < 4; ++r)
                R[ni * 4 + r] = relbase[(size_t)r * L_ + k0 + ni * 16];
    };

    auto compute = [&](int kt_, int p, float (&R)[16]) {
        const int k0 = kt_ * 64;
        const char* KsB = (const char*)Ks[p];
        const char* VsB = (const char*)Vs[p];

        // S strip = Q strip @ K^T  (swizzled LDS reads: 2 lanes/bank, free)
        f32x4 s[4];
#pragma unroll
        for (int ni = 0; ni < 4; ++ni) s[ni] = (f32x4){0.f, 0.f, 0.f, 0.f};
        __builtin_amdgcn_s_setprio(1);
#pragma unroll
        for (int ks = 0; ks < 2; ++ks) {
#pragma unroll
            for (int ni = 0; ni < 4; ++ni) {
                bf16x8 bk = *reinterpret_cast<const bf16x8*>(
                    KsB + (ni * 16 + lq) * 128 + (((ks * 4 + g) ^ (lq & 7)) * 16));
                s[ni] = __builtin_amdgcn_mfma_f32_16x16x32_bf16(aq[ks], bk, s[ni], 0, 0, 0);
            }
        }
        __builtin_amdgcn_s_setprio(0);

        // + rel bias (prefetched regs), mask
        float sv[4][4];
#pragma unroll
        for (int ni = 0; ni < 4; ++ni) {
            const int col = k0 + ni * 16 + lq;
            const bool ok = col < sl;
#pragma unroll
            for (int r = 0; r < 4; ++r)
                sv[ni][r] = ok ? (s[ni][r] + R[ni * 4 + r]) : NEGV;
        }

        // online softmax per row (16 lanes share a row)
#pragma unroll
        for (int r = 0; r < 4; ++r) {
            float rm = fmaxf(fmaxf(sv[0][r], sv[1][r]), fmaxf(sv[2][r], sv[3][r]));
            rm = fmaxf(rm, __shfl_xor(rm, 1, 16));
            rm = fmaxf(rm, __shfl_xor(rm, 2, 16));
            rm = fmaxf(rm, __shfl_xor(rm, 4, 16));
            rm = fmaxf(rm, __shfl_xor(rm, 8, 16));
            float mn = fmaxf(m_r[r], rm);
            float sc = __expf(m_r[r] - mn);
            float p_[4], rs = 0.f;
#pragma unroll
            for (int ni = 0; ni < 4; ++ni) {
                p_[ni] = __expf(sv[ni][r] - mn);
                rs += p_[ni];
            }
            rs += __shfl_xor(rs, 1, 16);
            rs += __shfl_xor(rs, 2, 16);
            rs += __shfl_xor(rs, 4, 16);
            rs += __shfl_xor(rs, 8, 16);
            l_r[r] = l_r[r] * sc + rs;
            m_r[r] = mn;
#pragma unroll
            for (int ni = 0; ni < 4; ++ni) {
                acc[ni][r] *= sc;
                Ps[(w * 16 + 4 * g + r) * 72 + ni * 16 + lq] = f2bf(p_[ni]);
            }
        }

        // O strip += P strip @ V tile (own-wave P strip, same-wave lgkm order)
        __builtin_amdgcn_s_setprio(1);
#pragma unroll
        for (int ks = 0; ks < 2; ++ks) {
            bf16x8 ap = *reinterpret_cast<const bf16x8*>(
                &Ps[(w * 16 + lq) * 72 + ks * 32 + g * 8]);
#pragma unroll
            for (int ni = 0; ni < 4; ++ni) {
                bf16x8 bv = *reinterpret_cast<const bf16x8*>(
                    VsB + (ni * 16 + lq) * 128 + (((ks * 4 + g) ^ (lq & 7)) * 16));
                acc[ni] = __builtin_amdgcn_mfma_f32_16x16x32_bf16(ap, bv, acc[ni], 0, 0, 0);
            }
        }
        __builtin_amdgcn_s_setprio(0);
    };

    // prologue: stage tile 0 + rel 0
    stage(0, 0);
    loadrel(0, relA);

    for (int kt = 0; kt < nkt; kt += 2) {
        {
            int tn = kt + 1 > ktmax ? ktmax : kt + 1;
            __builtin_amdgcn_s_barrier();                  // X: prev reads done
            stage(tn, 1);
            loadrel(tn, relB);
            __builtin_amdgcn_sched_barrier(0);
            asm volatile("s_waitcnt vmcnt(36)" ::: "memory");  // own tile-kt landed
            __builtin_amdgcn_s_barrier();                  // Y: all tile-kt landed
            compute(kt, 0, relA);
        }
        if (kt + 1 < nkt) {
            int tn = kt + 2 > ktmax ? ktmax : kt + 2;
            __builtin_amdgcn_s_barrier();                  // X
            stage(tn, 0);
            loadrel(tn, relA);
            __builtin_amdgcn_sched_barrier(0);
            asm volatile("s_waitcnt vmcnt(36)" ::: "memory");
            __builtin_amdgcn_s_barrier();                  // Y
            compute(kt + 1, 1, relB);
        }
    }

    // epilogue
    float inv[4];
#pragma unroll
    for (int r = 0; r < 4; ++r) inv[r] = 1.f / l_r[r];
#pragma unroll
    for (int ni = 0; ni < 4; ++ni)
#pragma unroll
        for (int r = 0; r < 4; ++r)
            ctx[(size_t)(b * L_ + q0 + w * 16 + 4 * g + r) * HID_ + h * D_ + ni * 16 + lq] =
                f2bf(acc[ni][r] * inv[r]);
}

// ---------------------------------------------------------------------------
// LayerNorm(2*x) over rows of 768; out f32 or bf16.
// ---------------------------------------------------------------------------
__global__ __launch_bounds__(256) void ln2_kernel(
    const float* __restrict__ in, const float* __restrict__ g,
    const float* __restrict__ bta, void* __restrict__ out, int bf16out)
{
    const int row = blockIdx.x;
    const float* x = in + (size_t)row * HID_;
    const int tid = threadIdx.x;

    float vals[3];
    float s = 0.f, ss = 0.f;
#pragma unroll
    for (int j = 0; j < 3; ++j) {
        float t = 2.f * x[tid + j * 256];
        vals[j] = t;
        s += t;
        ss += t * t;
    }
#pragma unroll
    for (int m = 1; m < 64; m <<= 1) {
        s += __shfl_xor(s, m, 64);
        ss += __shfl_xor(ss, m, 64);
    }
    __shared__ float sb[4], ssb[4];
    if ((tid & 63) == 0) { sb[tid >> 6] = s; ssb[tid >> 6] = ss; }
    __syncthreads();
    s = sb[0] + sb[1] + sb[2] + sb[3];
    ss = ssb[0] + ssb[1] + ssb[2] + ssb[3];
    const float mean = s * (1.f / 768.f);
    float var = ss * (1.f / 768.f) - mean * mean;
    if (var < 0.f) var = 0.f;
    const float invs = rsqrtf(var + 1e-5f);
    if (bf16out) {
        unsigned short* o = (unsigned short*)out;
#pragma unroll
        for (int j = 0; j < 3; ++j) {
            int c = tid + j * 256;
            o[(size_t)row * HID_ + c] = f2bf((vals[j] - mean) * invs * g[c] + bta[c]);
        }
    } else {
        float* o = (float*)out;
#pragma unroll
        for (int j = 0; j < 3; ++j) {
            int c = tid + j * 256;
            o[(size_t)row * HID_ + c] = (vals[j] - mean) * invs * g[c] + bta[c];
        }
    }
}

// ---------------------------------------------------------------------------
extern "C" void kernel_launch(void* const* d_in, const int* in_sizes, int n_in,
                              void* d_out, int out_size, void* d_ws, size_t ws_size,
                              hipStream_t stream) {
    const float* inp     = (const float*)d_in[0];
    const int*   seq_len = (const int*)d_in[1];
    const int*   lex_num = (const int*)d_in[2];
    const float* rel     = (const float*)d_in[3];
    const float* Wq = (const float*)d_in[4];
    const float* bq = (const float*)d_in[5];
    const float* Wk = (const float*)d_in[6];
    const float* bk = (const float*)d_in[7];
    const float* Wv = (const float*)d_in[8];
    const float* bv = (const float*)d_in[9];
    const float* Wo = (const float*)d_in[10];
    const float* bo = (const float*)d_in[11];
    const float* W0 = (const float*)d_in[12];
    const float* b0 = (const float*)d_in[13];
    const float* W1 = (const float*)d_in[14];
    const float* b1 = (const float*)d_in[15];
    const float* ln_g = (const float*)d_in[16];
    const float* ln_b = (const float*)d_in[17];
    float* out = (float*)d_out;

    // ---- workspace carve (bytes) ----
    char* W = (char*)d_ws;
    const size_t WT_SZ = (size_t)HID_ * HID_ * 2;
    unsigned short* Wt[6];
    for (int i = 0; i < 6; ++i) Wt[i] = (unsigned short*)(W + i * WT_SZ);
    size_t off = 6 * WT_SZ;
    const size_t TOK_BF = (size_t)B_ * L_ * HID_ * 2;
    unsigned short* qb  = (unsigned short*)(W + off); off += TOK_BF;
    unsigned short* kb  = (unsigned short*)(W + off); off += TOK_BF;
    unsigned short* vtb = (unsigned short*)(W + off); off += TOK_BF;
    unsigned short* Eb  = (unsigned short*)(W + off); off += TOK_BF;
    float* Fbuf = (float*)(W + off);

    unsigned short* Xb   = Eb;
    unsigned short* ctxb = Eb;
    unsigned short* y2b  = vtb;
    unsigned short* hb   = qb;

    convert_x_kernel<<<dim3(3072), dim3(256), 0, stream>>>(inp, Xb, (B_ * L_ * HID_) / 4);

    {
        WArgs wa;
        const float* ws_[6] = {Wq, Wk, Wv, Wo, W0, W1};
        for (int i = 0; i < 6; ++i) { wa.w[i] = ws_[i]; wa.wt[i] = Wt[i]; }
        transpose_w_kernel<<<dim3(12, 12, 6), dim3(256), 0, stream>>>(wa);
    }

    {
        GemmArgs ga;
        ga.j[0] = {Xb, Wt[0], bq, (void*)qb,  1, 0, SCALE_};
        ga.j[1] = {Xb, Wt[1], bk, (void*)kb,  1, 0, 1.f};
        ga.j[2] = {Xb, Wt[2], bv, (void*)vtb, 2, 0, 1.f};
        gemm_bf16_kernel<<<dim3(64, 6, 3), dim3(256), 0, stream>>>(ga);
    }

    attn_mfma_kernel<<<dim3(16, 48), dim3(256), 0, stream>>>(
        qb, kb, vtb, rel, seq_len, lex_num, ctxb);

    {
        GemmArgs ga;
        ga.j[0] = {ctxb, Wt[3], bo, (void*)Fbuf, 0, 0, 1.f};
        gemm_bf16_kernel<<<dim3(64, 6, 1), dim3(256), 0, stream>>>(ga);
    }
    ln2_kernel<<<dim3(4096), dim3(256), 0, stream>>>(Fbuf, ln_g, ln_b, (void*)y2b, 1);
    {
        GemmArgs ga;
        ga.j[0] = {y2b, Wt[4], b0, (void*)hb, 1, 1, 1.f};
        gemm_bf16_kernel<<<dim3(64, 6, 1), dim3(256), 0, stream>>>(ga);
    }
    {
        GemmArgs ga;
        ga.j[0] = {hb, Wt[5], b1, (void*)Fbuf, 0, 0, 1.f};
        gemm_bf16_kernel<<<dim3(64, 6, 1), dim3(256), 0, stream>>>(ga);
    }
    ln2_kernel<<<dim3(4096), dim3(256), 0, stream>>>(Fbuf, ln_g, ln_b, (void*)out, 0);
}